// Round 4
// baseline (367.672 us; speedup 1.0000x reference)
//
#include <hip/hip_runtime.h>
#include <math.h>

#define B_ 8
#define T_ 12
#define N_ 1024
#define D_ 64
#define E_ 64
#define M_ 16
#define BT_ (B_*T_)
#define ROWS_ (B_*T_*N_)
#define PAD 68    // fp32 LDS pitch
#define DPAD 72   // bf16 LDS pitch (144 B): 16B-aligned rows, 4-bank rotation/row

typedef __attribute__((ext_vector_type(8))) __bf16 bf16x8;
typedef __attribute__((ext_vector_type(4))) __bf16 bf16x4;
typedef __attribute__((ext_vector_type(4))) float f32x4;

__device__ __forceinline__ float elu1(float x) {
    return x > 0.0f ? x + 1.0f : __expf(x);
}

// ---------- K0a: tiny precompute + all weight bf16 conversions ----------
__global__ void k_precompute(const float* __restrict__ PHI, const float* __restrict__ WK,
                             const float* __restrict__ WV, const float* __restrict__ WQ,
                             const float* __restrict__ outW, const float* __restrict__ PW,
                             __bf16* __restrict__ phiKb, __bf16* __restrict__ Vtb,
                             __bf16* __restrict__ KtVtb, __bf16* __restrict__ WQb,
                             __bf16* __restrict__ outWb, __bf16* __restrict__ PWb) {
    __shared__ float sPhiK[M_ * E_];
    __shared__ float sV[M_ * D_];
    int tid = threadIdx.x;
    for (int i = tid; i < M_ * E_; i += 256) {
        int m = i >> 6, e = i & 63;
        float kk = 0.f, vv = 0.f;
        for (int j = 0; j < E_; ++j) {
            float p = PHI[m * E_ + j];
            kk += p * WK[e * E_ + j];
            vv += p * WV[e * E_ + j];
        }
        float pk = elu1(kk);
        sPhiK[i] = pk; phiKb[i] = (__bf16)pk;   // [m][e]
        sV[i] = vv;
    }
    __syncthreads();
    // Vtb [d][32] (k=m padded to 32 with zeros)
    for (int i = tid; i < 64 * 32; i += 256) {
        int d = i >> 5, m = i & 31;
        Vtb[i] = (m < M_) ? (__bf16)sV[m * 64 + d] : (__bf16)0.0f;
    }
    // KtVt [d][e]
    for (int i = tid; i < 4096; i += 256) {
        int d = i >> 6, e = i & 63;
        float acc = 0.f;
        for (int m = 0; m < M_; ++m) acc += sPhiK[m * 64 + e] * sV[m * 64 + d];
        KtVtb[i] = (__bf16)acc;
    }
    for (int i = tid; i < 4096; i += 256) {
        WQb[i] = (__bf16)WQ[i];      // [e][d]
        outWb[i] = (__bf16)outW[i];  // [o][d]
    }
    for (int i = tid; i < 64 * 192; i += 256) PWb[i] = (__bf16)PW[i];  // [o][192]
}

// ---------- K0b ----------
__global__ void k_dinv(const float* __restrict__ A, float* __restrict__ dinv) {
    int row = blockIdx.x;
    int tid = threadIdx.x;
    float s = 0.f;
    for (int i = tid; i < N_; i += 256) s += A[(size_t)row * N_ + i];
    for (int off = 32; off; off >>= 1) s += __shfl_xor(s, off, 64);
    __shared__ float red[4];
    if ((tid & 63) == 0) red[tid >> 6] = s;
    __syncthreads();
    if (tid == 0) dinv[row] = rsqrtf(red[0] + red[1] + red[2] + red[3] + 1e-12f);
}

// ---------- K1: fused spine: Q -> phiQ -> slot softmax -> mem_val
//             -> main_att + H -> @outW^T -> LN -> Hn + Ht, memval ----------
// 64-row tile per block; wave w owns rows w*16..+15 (wave-private in LDS).
__global__ void k_spine(const float* __restrict__ H, const __bf16* __restrict__ WQb,
                        const __bf16* __restrict__ phiKb, const __bf16* __restrict__ Vtb,
                        const __bf16* __restrict__ KtVtb, const __bf16* __restrict__ outWb,
                        const float* __restrict__ outb, const float* __restrict__ g,
                        const float* __restrict__ bb, __bf16* __restrict__ memval,
                        __bf16* __restrict__ Hn, __bf16* __restrict__ Ht) {
    __shared__ __align__(16) __bf16 As[64 * DPAD];   // H bf16 -> Hp bf16 (wave-private reuse)
    __shared__ __align__(16) __bf16 Ps[64 * DPAD];   // phiQ -> LN output (wave-private reuse)
    __shared__ __align__(16) __bf16 Ms[64 * DPAD];   // mem_val
    __shared__ __align__(16) __bf16 Pp[4][16 * 40];  // per-wave softmax P, K padded to 32
    int tid = threadIdx.x;
    int w = tid >> 6, lane = tid & 63, q = lane >> 4, lr = lane & 15;
    int rw = w * 16;
    const float* Hrow = H + (size_t)blockIdx.x * 4096;
    // stage H -> As bf16 (coalesced float4 reads)
    {
        int r = tid >> 2, c0 = (tid & 3) * 16;
        float4 f0 = *(const float4*)(Hrow + r * 64 + c0);
        float4 f1 = *(const float4*)(Hrow + r * 64 + c0 + 4);
        float4 f2 = *(const float4*)(Hrow + r * 64 + c0 + 8);
        float4 f3 = *(const float4*)(Hrow + r * 64 + c0 + 12);
        bf16x8 h0, h1;
        h0[0]=(__bf16)f0.x; h0[1]=(__bf16)f0.y; h0[2]=(__bf16)f0.z; h0[3]=(__bf16)f0.w;
        h0[4]=(__bf16)f1.x; h0[5]=(__bf16)f1.y; h0[6]=(__bf16)f1.z; h0[7]=(__bf16)f1.w;
        h1[0]=(__bf16)f2.x; h1[1]=(__bf16)f2.y; h1[2]=(__bf16)f2.z; h1[3]=(__bf16)f2.w;
        h1[4]=(__bf16)f3.x; h1[5]=(__bf16)f3.y; h1[6]=(__bf16)f3.z; h1[7]=(__bf16)f3.w;
        *(bf16x8*)&As[r * DPAD + c0] = h0;
        *(bf16x8*)&As[r * DPAD + c0 + 8] = h1;
    }
    // zero P pad region (wave-local)
#pragma unroll
    for (int i = 0; i < 10; ++i) Pp[w][lane * 10 + i] = (__bf16)0.0f;
    __syncthreads();   // barrier 1 (only cross-wave staging dependency)

    // ---- Q = H @ WQ^T (B-fragments direct from global; weights L2-hot) ----
    f32x4 qacc[4];
#pragma unroll
    for (int tj = 0; tj < 4; ++tj) qacc[tj] = (f32x4)(0.0f);
#pragma unroll
    for (int ks = 0; ks < 2; ++ks) {
        int kb = ks * 32 + q * 8;
        bf16x8 a = *(const bf16x8*)&As[(rw + lr) * DPAD + kb];
#pragma unroll
        for (int tj = 0; tj < 4; ++tj) {
            bf16x8 bv = *(const bf16x8*)(WQb + (size_t)(tj * 16 + lr) * 64 + kb);
            qacc[tj] = __builtin_amdgcn_mfma_f32_16x16x32_bf16(a, bv, qacc[tj], 0, 0, 0);
        }
    }
    // phiQ -> Ps (wave-private rows)
#pragma unroll
    for (int tj = 0; tj < 4; ++tj)
#pragma unroll
        for (int r = 0; r < 4; ++r)
            Ps[(rw + q * 4 + r) * DPAD + tj * 16 + lr] = (__bf16)elu1(qacc[tj][r]);

    // ---- S = phiQ @ phiK^T (16 slots), softmax over slots ----
    f32x4 sacc = (f32x4)(0.0f);
#pragma unroll
    for (int ks = 0; ks < 2; ++ks) {
        int kb = ks * 32 + q * 8;
        bf16x8 a = *(const bf16x8*)&Ps[(rw + lr) * DPAD + kb];
        bf16x8 bv = *(const bf16x8*)(phiKb + (size_t)lr * 64 + kb);
        sacc = __builtin_amdgcn_mfma_f32_16x16x32_bf16(a, bv, sacc, 0, 0, 0);
    }
#pragma unroll
    for (int r = 0; r < 4; ++r) {
        float s = sacc[r];
        float mx = s;
        mx = fmaxf(mx, __shfl_xor(mx, 1, 64)); mx = fmaxf(mx, __shfl_xor(mx, 2, 64));
        mx = fmaxf(mx, __shfl_xor(mx, 4, 64)); mx = fmaxf(mx, __shfl_xor(mx, 8, 64));
        float e = __expf(0.125f * (s - mx));
        float sum = e;
        sum += __shfl_xor(sum, 1, 64); sum += __shfl_xor(sum, 2, 64);
        sum += __shfl_xor(sum, 4, 64); sum += __shfl_xor(sum, 8, 64);
        Pp[w][(q * 4 + r) * 40 + lr] = (__bf16)(e / sum);
    }
    // ---- mem_val = P @ V  (K=32, zero-padded) ----
    f32x4 macc[4];
#pragma unroll
    for (int tj = 0; tj < 4; ++tj) macc[tj] = (f32x4)(0.0f);
    {
        bf16x8 ap = *(const bf16x8*)&Pp[w][lr * 40 + q * 8];
#pragma unroll
        for (int tj = 0; tj < 4; ++tj) {
            bf16x8 bv = *(const bf16x8*)(Vtb + (size_t)(tj * 16 + lr) * 32 + q * 8);
            macc[tj] = __builtin_amdgcn_mfma_f32_16x16x32_bf16(ap, bv, macc[tj], 0, 0, 0);
        }
    }
#pragma unroll
    for (int tj = 0; tj < 4; ++tj)
#pragma unroll
        for (int r = 0; r < 4; ++r)
            Ms[(rw + q * 4 + r) * DPAD + tj * 16 + lr] = (__bf16)macc[tj][r];

    // ---- main_att = phiQ @ KtV, Hp = main_att + H -> As(bf16) ----
    f32x4 aacc[4];
#pragma unroll
    for (int tj = 0; tj < 4; ++tj) aacc[tj] = (f32x4)(0.0f);
#pragma unroll
    for (int ks = 0; ks < 2; ++ks) {
        int kb = ks * 32 + q * 8;
        bf16x8 a = *(const bf16x8*)&Ps[(rw + lr) * DPAD + kb];
#pragma unroll
        for (int tj = 0; tj < 4; ++tj) {
            bf16x8 bv = *(const bf16x8*)(KtVtb + (size_t)(tj * 16 + lr) * 64 + kb);
            aacc[tj] = __builtin_amdgcn_mfma_f32_16x16x32_bf16(a, bv, aacc[tj], 0, 0, 0);
        }
    }
#pragma unroll
    for (int tj = 0; tj < 4; ++tj)
#pragma unroll
        for (int r = 0; r < 4; ++r) {
            float hp = aacc[tj][r] + Hrow[(rw + q * 4 + r) * 64 + tj * 16 + lr];
            As[(rw + q * 4 + r) * DPAD + tj * 16 + lr] = (__bf16)hp;
        }

    // ---- out = Hp @ outW^T + outb, LN -> Ps(bf16) ----
    f32x4 oacc[4];
#pragma unroll
    for (int tj = 0; tj < 4; ++tj) oacc[tj] = (f32x4)(0.0f);
#pragma unroll
    for (int ks = 0; ks < 2; ++ks) {
        int kb = ks * 32 + q * 8;
        bf16x8 a = *(const bf16x8*)&As[(rw + lr) * DPAD + kb];
#pragma unroll
        for (int tj = 0; tj < 4; ++tj) {
            bf16x8 bv = *(const bf16x8*)(outWb + (size_t)(tj * 16 + lr) * 64 + kb);
            oacc[tj] = __builtin_amdgcn_mfma_f32_16x16x32_bf16(a, bv, oacc[tj], 0, 0, 0);
        }
    }
    float biasv[4], gv[4], bv2[4];
#pragma unroll
    for (int tj = 0; tj < 4; ++tj) {
        int col = tj * 16 + lr;
        biasv[tj] = outb[col]; gv[tj] = g[col]; bv2[tj] = bb[col];
    }
#pragma unroll
    for (int r = 0; r < 4; ++r) {
        float v[4];
        float s = 0.f;
#pragma unroll
        for (int tj = 0; tj < 4; ++tj) { v[tj] = oacc[tj][r] + biasv[tj]; s += v[tj]; }
        s += __shfl_xor(s, 1, 64); s += __shfl_xor(s, 2, 64);
        s += __shfl_xor(s, 4, 64); s += __shfl_xor(s, 8, 64);
        float mu = s * (1.0f / 64.0f);
        float qv = 0.f;
#pragma unroll
        for (int tj = 0; tj < 4; ++tj) { float d = v[tj] - mu; qv += d * d; }
        qv += __shfl_xor(qv, 1, 64); qv += __shfl_xor(qv, 2, 64);
        qv += __shfl_xor(qv, 4, 64); qv += __shfl_xor(qv, 8, 64);
        float rstd = rsqrtf(qv * (1.0f / 64.0f) + 1e-5f);
#pragma unroll
        for (int tj = 0; tj < 4; ++tj)
            Ps[(rw + q * 4 + r) * DPAD + tj * 16 + lr] =
                (__bf16)((v[tj] - mu) * rstd * gv[tj] + bv2[tj]);
    }
    __syncthreads();   // barrier 2: Ms/Ps complete -> cooperative coalesced stores

    size_t base = (size_t)blockIdx.x * 4096;
    {
        int r = tid >> 2, c0 = (tid & 3) * 16;
        *(bf16x8*)(memval + base + (size_t)r * 64 + c0)     = *(const bf16x8*)&Ms[r * DPAD + c0];
        *(bf16x8*)(memval + base + (size_t)r * 64 + c0 + 8) = *(const bf16x8*)&Ms[r * DPAD + c0 + 8];
        *(bf16x8*)(Hn + base + (size_t)r * 64 + c0)         = *(const bf16x8*)&Ps[r * DPAD + c0];
        *(bf16x8*)(Hn + base + (size_t)r * 64 + c0 + 8)     = *(const bf16x8*)&Ps[r * DPAD + c0 + 8];
    }
    int bt = blockIdx.x >> 4, n0b = (blockIdx.x & 15) * 64;
    size_t tbase = (size_t)bt * 64 * N_;
#pragma unroll
    for (int i = 0; i < 2; ++i) {
        int d = (tid >> 3) + i * 32;
        int n8 = (tid & 7) * 8;
        bf16x8 v;
#pragma unroll
        for (int j = 0; j < 8; ++j) {
            int jj = (j + tid) & 7;
            v[jj] = Ps[(n8 + jj) * DPAD + d];
        }
        *(bf16x8*)(Ht + tbase + (size_t)d * N_ + n0b + n8) = v;
    }
}

// ---------- K2: mv = mean_t memval ----------
__global__ void k_mvred(const __bf16* __restrict__ memval, __bf16* __restrict__ mvb) {
    int idx = (blockIdx.x * 256 + threadIdx.x) * 4;   // over B*N*64
    int b = idx >> 16;              // N*64 = 65536
    int off = idx & 65535;
    const __bf16* p = memval + (size_t)b * T_ * 65536 + off;
    float a0 = 0.f, a1 = 0.f, a2 = 0.f, a3 = 0.f;
#pragma unroll
    for (int t = 0; t < T_; ++t) {
        bf16x4 v = *(const bf16x4*)(p + (size_t)t * 65536);
        a0 += (float)v[0]; a1 += (float)v[1]; a2 += (float)v[2]; a3 += (float)v[3];
    }
    bf16x4 o;
    o[0] = (__bf16)(a0 * (1.0f / 12.0f)); o[1] = (__bf16)(a1 * (1.0f / 12.0f));
    o[2] = (__bf16)(a2 * (1.0f / 12.0f)); o[3] = (__bf16)(a3 * (1.0f / 12.0f));
    *(bf16x4*)(mvb + idx) = o;
}

// ---------- K3: MFMA A_dynamic + A_fused, in-register row softmax ----------
__global__ void k_adyn_mfma(const __bf16* __restrict__ mvb_all, const float* __restrict__ Ast,
                            const float* __restrict__ dinv, const float* __restrict__ beta,
                            float* __restrict__ Adyn, float* __restrict__ Afu,
                            __bf16* __restrict__ Afb) {
    __shared__ __align__(16) __bf16 As[16 * DPAD];
    __shared__ __align__(16) __bf16 Bs[256 * DPAD];
    __shared__ float redm[4][16];
    __shared__ float reds[4][16];
    int tid = threadIdx.x;
    int b = blockIdx.x >> 6, n0 = (blockIdx.x & 63) * 16;
    const __bf16* mvb = mvb_all + (size_t)b * N_ * 64;
    {
        int r = tid >> 4, c4 = (tid & 15) * 4;
        *(bf16x4*)&As[r * DPAD + c4] = *(const bf16x4*)(mvb + (size_t)(n0 + r) * 64 + c4);
    }
    int w = tid >> 6, lane = tid & 63, q = lane >> 4, lr = lane & 15;
    f32x4 acc[4][4];
#pragma unroll
    for (int c = 0; c < 4; ++c)
#pragma unroll
        for (int tj = 0; tj < 4; ++tj) acc[c][tj] = (f32x4)(0.0f);
    int brow = tid >> 3, bcol = (tid & 7) * 8;
    for (int c = 0; c < 4; ++c) {
        __syncthreads();
#pragma unroll
        for (int i = 0; i < 8; ++i) {
            int r = brow + i * 32;
            *(bf16x8*)&Bs[r * DPAD + bcol] = *(const bf16x8*)(mvb + (size_t)(c * 256 + r) * 64 + bcol);
        }
        __syncthreads();
#pragma unroll
        for (int ks = 0; ks < 2; ++ks) {
            int kb = ks * 32 + q * 8;
            bf16x8 a0 = *(const bf16x8*)&As[lr * DPAD + kb];
#pragma unroll
            for (int tj = 0; tj < 4; ++tj) {
                bf16x8 bv = *(const bf16x8*)&Bs[(w * 64 + tj * 16 + lr) * DPAD + kb];
                acc[c][tj] = __builtin_amdgcn_mfma_f32_16x16x32_bf16(a0, bv, acc[c][tj], 0, 0, 0);
            }
        }
    }
    float mrow[4];
#pragma unroll
    for (int rr = 0; rr < 4; ++rr) {
        float m = -3.4e38f;
#pragma unroll
        for (int c = 0; c < 4; ++c)
#pragma unroll
            for (int tj = 0; tj < 4; ++tj) m = fmaxf(m, acc[c][tj][rr]);
        m = fmaxf(m, __shfl_xor(m, 1, 64)); m = fmaxf(m, __shfl_xor(m, 2, 64));
        m = fmaxf(m, __shfl_xor(m, 4, 64)); m = fmaxf(m, __shfl_xor(m, 8, 64));
        mrow[rr] = m;
    }
    if (lr == 0) {
#pragma unroll
        for (int rr = 0; rr < 4; ++rr) redm[w][q * 4 + rr] = mrow[rr];
    }
    __syncthreads();
    float mg[4];
#pragma unroll
    for (int rr = 0; rr < 4; ++rr) {
        int row = q * 4 + rr;
        mg[rr] = fmaxf(fmaxf(redm[0][row], redm[1][row]), fmaxf(redm[2][row], redm[3][row]));
    }
    float srow[4] = {0.f, 0.f, 0.f, 0.f};
#pragma unroll
    for (int c = 0; c < 4; ++c)
#pragma unroll
        for (int tj = 0; tj < 4; ++tj)
#pragma unroll
            for (int rr = 0; rr < 4; ++rr) {
                float e = __expf(0.125f * (acc[c][tj][rr] - mg[rr]));
                acc[c][tj][rr] = e;
                srow[rr] += e;
            }
#pragma unroll
    for (int rr = 0; rr < 4; ++rr) {
        float s = srow[rr];
        s += __shfl_xor(s, 1, 64); s += __shfl_xor(s, 2, 64);
        s += __shfl_xor(s, 4, 64); s += __shfl_xor(s, 8, 64);
        srow[rr] = s;
    }
    if (lr == 0) {
#pragma unroll
        for (int rr = 0; rr < 4; ++rr) reds[w][q * 4 + rr] = srow[rr];
    }
    __syncthreads();
    float inv[4];
#pragma unroll
    for (int rr = 0; rr < 4; ++rr) {
        int row = q * 4 + rr;
        inv[rr] = 1.0f / (reds[0][row] + reds[1][row] + reds[2][row] + reds[3][row]);
    }
    float bta = fminf(fmaxf(beta[0], 0.0f), 1.0f);
    float omb = 1.0f - bta;
    float dc[4][4];
#pragma unroll
    for (int c = 0; c < 4; ++c)
#pragma unroll
        for (int tj = 0; tj < 4; ++tj) dc[c][tj] = dinv[c * 256 + w * 64 + tj * 16 + lr];
#pragma unroll
    for (int rr = 0; rr < 4; ++rr) {
        int n = n0 + q * 4 + rr;
        float dn = omb * dinv[n];
        size_t ro = ((size_t)b * N_ + n) * N_;
        const float* arow = Ast + (size_t)n * N_;
#pragma unroll
        for (int c = 0; c < 4; ++c)
#pragma unroll
            for (int tj = 0; tj < 4; ++tj) {
                int col = c * 256 + w * 64 + tj * 16 + lr;
                float p = acc[c][tj][rr] * inv[rr];
                float fu = bta * p + dn * arow[col] * dc[c][tj];
                Adyn[ro + col] = p;
                Afu[ro + col] = fu;
                Afb[ro + col] = (__bf16)fu;
            }
    }
}

// ---------- K4: hop 1 — direct-to-register K-loop (no LDS, no barriers) ----------
__global__ void k_diffuse1(const __bf16* __restrict__ Afb, const __bf16* __restrict__ Xt,
                           __bf16* __restrict__ Xn_out, __bf16* __restrict__ Xt_out) {
    __shared__ __align__(16) __bf16 Cs[128 * DPAD];
    int tid = threadIdx.x;
    int bt = blockIdx.y, b = bt / T_;
    int n0 = blockIdx.x * 128;
    int w = tid >> 6, lane = tid & 63, q = lane >> 4, lr = lane & 15;
    int mw = w * 32;
    const __bf16* A = Afb + (size_t)b * N_ * N_ + (size_t)n0 * N_;
    const __bf16* X = Xt + (size_t)bt * 64 * N_;
    const __bf16* a0p = A + (size_t)(mw + lr) * N_ + q * 8;
    const __bf16* a1p = A + (size_t)(mw + 16 + lr) * N_ + q * 8;
    const __bf16* b0p = X + (size_t)(lr) * N_ + q * 8;
    const __bf16* b1p = X + (size_t)(16 + lr) * N_ + q * 8;
    const __bf16* b2p = X + (size_t)(32 + lr) * N_ + q * 8;
    const __bf16* b3p = X + (size_t)(48 + lr) * N_ + q * 8;
    f32x4 acc[2][4];
#pragma unroll
    for (int i = 0; i < 2; ++i)
#pragma unroll
        for (int j = 0; j < 4; ++j) acc[i][j] = (f32x4)(0.0f);
#pragma unroll 8
    for (int kk = 0; kk < 32; ++kk) {
        int k = kk * 32;
        bf16x8 a0 = *(const bf16x8*)(a0p + k);
        bf16x8 a1 = *(const bf16x8*)(a1p + k);
        bf16x8 b0 = *(const bf16x8*)(b0p + k);
        bf16x8 b1 = *(const bf16x8*)(b1p + k);
        bf16x8 b2 = *(const bf16x8*)(b2p + k);
        bf16x8 b3 = *(const bf16x8*)(b3p + k);
        acc[0][0] = __builtin_amdgcn_mfma_f32_16x16x32_bf16(a0, b0, acc[0][0], 0, 0, 0);
        acc[1][0] = __builtin_amdgcn_mfma_f32_16x16x32_bf16(a1, b0, acc[1][0], 0, 0, 0);
        acc[0][1] = __builtin_amdgcn_mfma_f32_16x16x32_bf16(a0, b1, acc[0][1], 0, 0, 0);
        acc[1][1] = __builtin_amdgcn_mfma_f32_16x16x32_bf16(a1, b1, acc[1][1], 0, 0, 0);
        acc[0][2] = __builtin_amdgcn_mfma_f32_16x16x32_bf16(a0, b2, acc[0][2], 0, 0, 0);
        acc[1][2] = __builtin_amdgcn_mfma_f32_16x16x32_bf16(a1, b2, acc[1][2], 0, 0, 0);
        acc[0][3] = __builtin_amdgcn_mfma_f32_16x16x32_bf16(a0, b3, acc[0][3], 0, 0, 0);
        acc[1][3] = __builtin_amdgcn_mfma_f32_16x16x32_bf16(a1, b3, acc[1][3], 0, 0, 0);
    }
#pragma unroll
    for (int ti = 0; ti < 2; ++ti)
#pragma unroll
        for (int tj = 0; tj < 4; ++tj)
#pragma unroll
            for (int r = 0; r < 4; ++r)
                Cs[(mw + ti * 16 + q * 4 + r) * DPAD + tj * 16 + lr] = (__bf16)acc[ti][tj][r];
    __syncthreads();
    size_t obase = (size_t)bt * N_ * 64 + (size_t)n0 * 64;
#pragma unroll
    for (int i = 0; i < 2; ++i) {
        int r = (tid >> 2) + i * 64, c0 = (tid & 3) * 16;
        *(bf16x8*)(Xn_out + obase + (size_t)r * 64 + c0)     = *(const bf16x8*)&Cs[r * DPAD + c0];
        *(bf16x8*)(Xn_out + obase + (size_t)r * 64 + c0 + 8) = *(const bf16x8*)&Cs[r * DPAD + c0 + 8];
    }
    size_t tbase = (size_t)bt * 64 * N_;
#pragma unroll
    for (int i = 0; i < 4; ++i) {
        int d = (tid >> 4) + i * 16;
        int n8 = (tid & 15) * 8;
        bf16x8 v;
#pragma unroll
        for (int j = 0; j < 8; ++j) {
            int jj = (j + tid) & 7;
            v[jj] = Cs[(n8 + jj) * DPAD + d];
        }
        *(bf16x8*)(Xt_out + tbase + (size_t)d * N_ + n0 + n8) = v;
    }
}

// ---------- K5: hop 2 + proj + LN fused (X2 never leaves the block) ----------
__global__ void k_diffuse2_proj(const __bf16* __restrict__ Afb, const __bf16* __restrict__ X1t,
                                const __bf16* __restrict__ Hn, const __bf16* __restrict__ X1n,
                                const __bf16* __restrict__ PWb, const float* __restrict__ pb,
                                const float* __restrict__ g, const float* __restrict__ bb,
                                float* __restrict__ out) {
    __shared__ __align__(16) __bf16 Cs[128 * DPAD];
    int tid = threadIdx.x;
    int bt = blockIdx.y, b = bt / T_;
    int n0 = blockIdx.x * 128;
    int w = tid >> 6, lane = tid & 63, q = lane >> 4, lr = lane & 15;
    int mw = w * 32;
    const __bf16* A = Afb + (size_t)b * N_ * N_ + (size_t)n0 * N_;
    const __bf16* X = X1t + (size_t)bt * 64 * N_;
    const __bf16* a0p = A + (size_t)(mw + lr) * N_ + q * 8;
    const __bf16* a1p = A + (size_t)(mw + 16 + lr) * N_ + q * 8;
    const __bf16* b0p = X + (size_t)(lr) * N_ + q * 8;
    const __bf16* b1p = X + (size_t)(16 + lr) * N_ + q * 8;
    const __bf16* b2p = X + (size_t)(32 + lr) * N_ + q * 8;
    const __bf16* b3p = X + (size_t)(48 + lr) * N_ + q * 8;
    f32x4 acc[2][4];
#pragma unroll
    for (int i = 0; i < 2; ++i)
#pragma unroll
        for (int j = 0; j < 4; ++j) acc[i][j] = (f32x4)(0.0f);
#pragma unroll 8
    for (int kk = 0; kk < 32; ++kk) {
        int k = kk * 32;
        bf16x8 a0 = *(const bf16x8*)(a0p + k);
        bf16x8 a1 = *(const bf16x8*)(a1p + k);
        bf16x8 b0 = *(const bf16x8*)(b0p + k);
        bf16x8 b1 = *(const bf16x8*)(b1p + k);
        bf16x8 b2 = *(const bf16x8*)(b2p + k);
        bf16x8 b3 = *(const bf16x8*)(b3p + k);
        acc[0][0] = __builtin_amdgcn_mfma_f32_16x16x32_bf16(a0, b0, acc[0][0], 0, 0, 0);
        acc[1][0] = __builtin_amdgcn_mfma_f32_16x16x32_bf16(a1, b0, acc[1][0], 0, 0, 0);
        acc[0][1] = __builtin_amdgcn_mfma_f32_16x16x32_bf16(a0, b1, acc[0][1], 0, 0, 0);
        acc[1][1] = __builtin_amdgcn_mfma_f32_16x16x32_bf16(a1, b1, acc[1][1], 0, 0, 0);
        acc[0][2] = __builtin_amdgcn_mfma_f32_16x16x32_bf16(a0, b2, acc[0][2], 0, 0, 0);
        acc[1][2] = __builtin_amdgcn_mfma_f32_16x16x32_bf16(a1, b2, acc[1][2], 0, 0, 0);
        acc[0][3] = __builtin_amdgcn_mfma_f32_16x16x32_bf16(a0, b3, acc[0][3], 0, 0, 0);
        acc[1][3] = __builtin_amdgcn_mfma_f32_16x16x32_bf16(a1, b3, acc[1][3], 0, 0, 0);
    }
    // X2 -> LDS (bf16, wave-private rows; proj A-frags read back wave-locally)
#pragma unroll
    for (int ti = 0; ti < 2; ++ti)
#pragma unroll
        for (int tj = 0; tj < 4; ++tj)
#pragma unroll
            for (int r = 0; r < 4; ++r)
                Cs[(mw + ti * 16 + q * 4 + r) * DPAD + tj * 16 + lr] = (__bf16)acc[ti][tj][r];
    // proj: cat(H', X1, X2) @ PW^T
    f32x4 pacc[2][4];
#pragma unroll
    for (int i = 0; i < 2; ++i)
#pragma unroll
        for (int j = 0; j < 4; ++j) pacc[i][j] = (f32x4)(0.0f);
    size_t row0 = (size_t)bt * N_ + n0;
#pragma unroll
    for (int c = 0; c < 2; ++c) {
        const __bf16* S = (c ? X1n : Hn) + row0 * 64;
#pragma unroll
        for (int ks = 0; ks < 2; ++ks) {
            int kb = ks * 32 + q * 8;
            bf16x8 a0 = *(const bf16x8*)(S + (size_t)(mw + lr) * 64 + kb);
            bf16x8 a1 = *(const bf16x8*)(S + (size_t)(mw + 16 + lr) * 64 + kb);
#pragma unroll
            for (int tj = 0; tj < 4; ++tj) {
                bf16x8 bv = *(const bf16x8*)(PWb + (size_t)(tj * 16 + lr) * 192 + c * 64 + kb);
                pacc[0][tj] = __builtin_amdgcn_mfma_f32_16x16x32_bf16(a0, bv, pacc[0][tj], 0, 0, 0);
                pacc[1][tj] = __builtin_amdgcn_mfma_f32_16x16x32_bf16(a1, bv, pacc[1][tj], 0, 0, 0);
            }
        }
    }
#pragma unroll
    for (int ks = 0; ks < 2; ++ks) {
        int kb = ks * 32 + q * 8;
        bf16x8 a0 = *(const bf16x8*)&Cs[(mw + lr) * DPAD + kb];
        bf16x8 a1 = *(const bf16x8*)&Cs[(mw + 16 + lr) * DPAD + kb];
#pragma unroll
        for (int tj = 0; tj < 4; ++tj) {
            bf16x8 bv = *(const bf16x8*)(PWb + (size_t)(tj * 16 + lr) * 192 + 128 + kb);
            pacc[0][tj] = __builtin_amdgcn_mfma_f32_16x16x32_bf16(a0, bv, pacc[0][tj], 0, 0, 0);
            pacc[1][tj] = __builtin_amdgcn_mfma_f32_16x16x32_bf16(a1, bv, pacc[1][tj], 0, 0, 0);
        }
    }
    // bias + LN epilogue
    float pbv[4], gv[4], bv2[4];
#pragma unroll
    for (int tj = 0; tj < 4; ++tj) {
        int col = tj * 16 + lr;
        pbv[tj] = pb[col]; gv[tj] = g[col]; bv2[tj] = bb[col];
    }
#pragma unroll
    for (int ti = 0; ti < 2; ++ti) {
#pragma unroll
        for (int r = 0; r < 4; ++r) {
            float v[4];
            float s = 0.f;
#pragma unroll
            for (int tj = 0; tj < 4; ++tj) { v[tj] = pacc[ti][tj][r] + pbv[tj]; s += v[tj]; }
            s += __shfl_xor(s, 1, 64); s += __shfl_xor(s, 2, 64);
            s += __shfl_xor(s, 4, 64); s += __shfl_xor(s, 8, 64);
            float mu = s * (1.0f / 64.0f);
            float qv = 0.f;
#pragma unroll
            for (int tj = 0; tj < 4; ++tj) { float d = v[tj] - mu; qv += d * d; }
            qv += __shfl_xor(qv, 1, 64); qv += __shfl_xor(qv, 2, 64);
            qv += __shfl_xor(qv, 4, 64); qv += __shfl_xor(qv, 8, 64);
            float rstd = rsqrtf(qv * (1.0f / 64.0f) + 1e-5f);
            size_t row = row0 + mw + ti * 16 + q * 4 + r;
#pragma unroll
            for (int tj = 0; tj < 4; ++tj)
                out[row * 64 + tj * 16 + lr] = (v[tj] - mu) * rstd * gv[tj] + bv2[tj];
        }
    }
}

// ---------- launch ----------
extern "C" void kernel_launch(void* const* d_in, const int* in_sizes, int n_in,
                              void* d_out, int out_size, void* d_ws, size_t ws_size,
                              hipStream_t stream) {
    const float* H    = (const float*)d_in[0];
    const float* Ast  = (const float*)d_in[1];
    const float* WQ   = (const float*)d_in[2];
    const float* WK   = (const float*)d_in[3];
    const float* WV   = (const float*)d_in[4];
    const float* PHI  = (const float*)d_in[5];
    const float* outW = (const float*)d_in[6];
    const float* outb = (const float*)d_in[7];
    const float* smag = (const float*)d_in[8];
    const float* smab = (const float*)d_in[9];
    const float* beta = (const float*)d_in[10];
    const float* PW   = (const float*)d_in[11];
    const float* pb   = (const float*)d_in[12];
    const float* aggg = (const float*)d_in[13];
    const float* aggb = (const float*)d_in[14];

    float* out  = (float*)d_out;
    float* Hsp  = out;
    float* Adyn = out + (size_t)ROWS_ * 64;
    float* Afu  = Adyn + (size_t)B_ * N_ * N_;

    __bf16* memval = (__bf16*)d_ws;                    // [BT,N,64]
    __bf16* Hn   = memval + (size_t)ROWS_ * 64;
    __bf16* Ht   = Hn + (size_t)ROWS_ * 64;
    __bf16* X1n  = Ht + (size_t)ROWS_ * 64;
    __bf16* X1t  = X1n + (size_t)ROWS_ * 64;
    __bf16* Afb  = X1t + (size_t)ROWS_ * 64;           // [B,N,N]
    __bf16* mvb  = Afb + (size_t)B_ * N_ * N_;         // [B,N,64]
    __bf16* phiKb = mvb + (size_t)B_ * N_ * 64;
    __bf16* Vtb   = phiKb + M_ * E_;                   // [64][32] padded
    __bf16* KtVtb = Vtb + 64 * 32;
    __bf16* WQb   = KtVtb + 4096;
    __bf16* outWb = WQb + 4096;
    __bf16* PWb   = outWb + 4096;                      // [64][192]
    float*  dinv  = (float*)(PWb + 64 * 192);

    k_precompute<<<1, 256, 0, stream>>>(PHI, WK, WV, WQ, outW, PW,
                                        phiKb, Vtb, KtVtb, WQb, outWb, PWb);
    k_dinv<<<N_, 256, 0, stream>>>(Ast, dinv);
    k_spine<<<ROWS_ / 64, 256, 0, stream>>>(H, WQb, phiKb, Vtb, KtVtb, outWb,
                                            outb, smag, smab, memval, Hn, Ht);
    k_mvred<<<(B_ * N_ * 64 / 4) / 256, 256, 0, stream>>>(memval, mvb);
    k_adyn_mfma<<<B_ * N_ / 16, 256, 0, stream>>>(mvb, Ast, dinv, beta, Adyn, Afu, Afb);
    k_diffuse1<<<dim3(8, BT_), 256, 0, stream>>>(Afb, Ht, X1n, X1t);
    k_diffuse2_proj<<<dim3(8, BT_), 256, 0, stream>>>(Afb, X1t, Hn, X1n, PWb,
                                                      pb, aggg, aggb, Hsp);
}

// Round 5
// 284.487 us; speedup vs baseline: 1.2924x; 1.2924x over previous
//
#include <hip/hip_runtime.h>
#include <math.h>

#define B_ 8
#define T_ 12
#define N_ 1024
#define D_ 64
#define E_ 64
#define M_ 16
#define BT_ (B_*T_)
#define ROWS_ (B_*T_*N_)
#define DPAD 72   // bf16 LDS pitch (144 B): 16B-aligned rows, 4-bank rotation/row

typedef __attribute__((ext_vector_type(8))) __bf16 bf16x8;
typedef __attribute__((ext_vector_type(4))) __bf16 bf16x4;
typedef __attribute__((ext_vector_type(4))) float f32x4;

__device__ __forceinline__ float elu1(float x) {
    return x > 0.0f ? x + 1.0f : __expf(x);
}

// ---------- K0a: tiny precompute + all weight bf16 conversions ----------
__global__ void k_precompute(const float* __restrict__ PHI, const float* __restrict__ WK,
                             const float* __restrict__ WV, const float* __restrict__ WQ,
                             const float* __restrict__ outW, const float* __restrict__ PW,
                             __bf16* __restrict__ phiKb, __bf16* __restrict__ Vtb,
                             __bf16* __restrict__ KtVtb, __bf16* __restrict__ WQb,
                             __bf16* __restrict__ outWb, __bf16* __restrict__ PWb) {
    __shared__ float sPhiK[M_ * E_];
    __shared__ float sV[M_ * D_];
    int tid = threadIdx.x;
    for (int i = tid; i < M_ * E_; i += 256) {
        int m = i >> 6, e = i & 63;
        float kk = 0.f, vv = 0.f;
        for (int j = 0; j < E_; ++j) {
            float p = PHI[m * E_ + j];
            kk += p * WK[e * E_ + j];
            vv += p * WV[e * E_ + j];
        }
        float pk = elu1(kk);
        sPhiK[i] = pk; phiKb[i] = (__bf16)pk;   // [m][e]
        sV[i] = vv;
    }
    __syncthreads();
    // Vtb [d][32] (k=m padded to 32 with zeros)
    for (int i = tid; i < 64 * 32; i += 256) {
        int d = i >> 5, m = i & 31;
        Vtb[i] = (m < M_) ? (__bf16)sV[m * 64 + d] : (__bf16)0.0f;
    }
    // KtVt [d][e]
    for (int i = tid; i < 4096; i += 256) {
        int d = i >> 6, e = i & 63;
        float acc = 0.f;
        for (int m = 0; m < M_; ++m) acc += sPhiK[m * 64 + e] * sV[m * 64 + d];
        KtVtb[i] = (__bf16)acc;
    }
    for (int i = tid; i < 4096; i += 256) {
        WQb[i] = (__bf16)WQ[i];      // [e][d]
        outWb[i] = (__bf16)outW[i];  // [o][d]
    }
    for (int i = tid; i < 64 * 192; i += 256) PWb[i] = (__bf16)PW[i];  // [o][192]
}

// ---------- K0b ----------
__global__ void k_dinv(const float* __restrict__ A, float* __restrict__ dinv) {
    int row = blockIdx.x;
    int tid = threadIdx.x;
    float s = 0.f;
    for (int i = tid; i < N_; i += 256) s += A[(size_t)row * N_ + i];
    for (int off = 32; off; off >>= 1) s += __shfl_xor(s, off, 64);
    __shared__ float red[4];
    if ((tid & 63) == 0) red[tid >> 6] = s;
    __syncthreads();
    if (tid == 0) dinv[row] = rsqrtf(red[0] + red[1] + red[2] + red[3] + 1e-12f);
}

// ---------- K1: fused spine ----------
__global__ void k_spine(const float* __restrict__ H, const __bf16* __restrict__ WQb,
                        const __bf16* __restrict__ phiKb, const __bf16* __restrict__ Vtb,
                        const __bf16* __restrict__ KtVtb, const __bf16* __restrict__ outWb,
                        const float* __restrict__ outb, const float* __restrict__ g,
                        const float* __restrict__ bb, __bf16* __restrict__ memval,
                        __bf16* __restrict__ Hn, __bf16* __restrict__ Ht) {
    __shared__ __align__(16) __bf16 As[64 * DPAD];   // H bf16 -> Hp bf16 (wave-private reuse)
    __shared__ __align__(16) __bf16 Ps[64 * DPAD];   // phiQ -> LN output (wave-private reuse)
    __shared__ __align__(16) __bf16 Ms[64 * DPAD];   // mem_val
    __shared__ __align__(16) __bf16 Pp[4][16 * 40];  // per-wave softmax P, K padded to 32
    int tid = threadIdx.x;
    int w = tid >> 6, lane = tid & 63, q = lane >> 4, lr = lane & 15;
    int rw = w * 16;
    const float* Hrow = H + (size_t)blockIdx.x * 4096;
    {
        int r = tid >> 2, c0 = (tid & 3) * 16;
        float4 f0 = *(const float4*)(Hrow + r * 64 + c0);
        float4 f1 = *(const float4*)(Hrow + r * 64 + c0 + 4);
        float4 f2 = *(const float4*)(Hrow + r * 64 + c0 + 8);
        float4 f3 = *(const float4*)(Hrow + r * 64 + c0 + 12);
        bf16x8 h0, h1;
        h0[0]=(__bf16)f0.x; h0[1]=(__bf16)f0.y; h0[2]=(__bf16)f0.z; h0[3]=(__bf16)f0.w;
        h0[4]=(__bf16)f1.x; h0[5]=(__bf16)f1.y; h0[6]=(__bf16)f1.z; h0[7]=(__bf16)f1.w;
        h1[0]=(__bf16)f2.x; h1[1]=(__bf16)f2.y; h1[2]=(__bf16)f2.z; h1[3]=(__bf16)f2.w;
        h1[4]=(__bf16)f3.x; h1[5]=(__bf16)f3.y; h1[6]=(__bf16)f3.z; h1[7]=(__bf16)f3.w;
        *(bf16x8*)&As[r * DPAD + c0] = h0;
        *(bf16x8*)&As[r * DPAD + c0 + 8] = h1;
    }
#pragma unroll
    for (int i = 0; i < 10; ++i) Pp[w][lane * 10 + i] = (__bf16)0.0f;
    __syncthreads();

    // ---- Q = H @ WQ^T ----
    f32x4 qacc[4];
#pragma unroll
    for (int tj = 0; tj < 4; ++tj) qacc[tj] = (f32x4)(0.0f);
#pragma unroll
    for (int ks = 0; ks < 2; ++ks) {
        int kb = ks * 32 + q * 8;
        bf16x8 a = *(const bf16x8*)&As[(rw + lr) * DPAD + kb];
#pragma unroll
        for (int tj = 0; tj < 4; ++tj) {
            bf16x8 bv = *(const bf16x8*)(WQb + (size_t)(tj * 16 + lr) * 64 + kb);
            qacc[tj] = __builtin_amdgcn_mfma_f32_16x16x32_bf16(a, bv, qacc[tj], 0, 0, 0);
        }
    }
#pragma unroll
    for (int tj = 0; tj < 4; ++tj)
#pragma unroll
        for (int r = 0; r < 4; ++r)
            Ps[(rw + q * 4 + r) * DPAD + tj * 16 + lr] = (__bf16)elu1(qacc[tj][r]);

    // ---- S = phiQ @ phiK^T, softmax over slots ----
    f32x4 sacc = (f32x4)(0.0f);
#pragma unroll
    for (int ks = 0; ks < 2; ++ks) {
        int kb = ks * 32 + q * 8;
        bf16x8 a = *(const bf16x8*)&Ps[(rw + lr) * DPAD + kb];
        bf16x8 bv = *(const bf16x8*)(phiKb + (size_t)lr * 64 + kb);
        sacc = __builtin_amdgcn_mfma_f32_16x16x32_bf16(a, bv, sacc, 0, 0, 0);
    }
#pragma unroll
    for (int r = 0; r < 4; ++r) {
        float s = sacc[r];
        float mx = s;
        mx = fmaxf(mx, __shfl_xor(mx, 1, 64)); mx = fmaxf(mx, __shfl_xor(mx, 2, 64));
        mx = fmaxf(mx, __shfl_xor(mx, 4, 64)); mx = fmaxf(mx, __shfl_xor(mx, 8, 64));
        float e = __expf(0.125f * (s - mx));
        float sum = e;
        sum += __shfl_xor(sum, 1, 64); sum += __shfl_xor(sum, 2, 64);
        sum += __shfl_xor(sum, 4, 64); sum += __shfl_xor(sum, 8, 64);
        Pp[w][(q * 4 + r) * 40 + lr] = (__bf16)(e / sum);
    }
    // ---- mem_val = P @ V ----
    f32x4 macc[4];
#pragma unroll
    for (int tj = 0; tj < 4; ++tj) macc[tj] = (f32x4)(0.0f);
    {
        bf16x8 ap = *(const bf16x8*)&Pp[w][lr * 40 + q * 8];
#pragma unroll
        for (int tj = 0; tj < 4; ++tj) {
            bf16x8 bv = *(const bf16x8*)(Vtb + (size_t)(tj * 16 + lr) * 32 + q * 8);
            macc[tj] = __builtin_amdgcn_mfma_f32_16x16x32_bf16(ap, bv, macc[tj], 0, 0, 0);
        }
    }
#pragma unroll
    for (int tj = 0; tj < 4; ++tj)
#pragma unroll
        for (int r = 0; r < 4; ++r)
            Ms[(rw + q * 4 + r) * DPAD + tj * 16 + lr] = (__bf16)macc[tj][r];

    // ---- main_att = phiQ @ KtV, Hp = main_att + H ----
    f32x4 aacc[4];
#pragma unroll
    for (int tj = 0; tj < 4; ++tj) aacc[tj] = (f32x4)(0.0f);
#pragma unroll
    for (int ks = 0; ks < 2; ++ks) {
        int kb = ks * 32 + q * 8;
        bf16x8 a = *(const bf16x8*)&Ps[(rw + lr) * DPAD + kb];
#pragma unroll
        for (int tj = 0; tj < 4; ++tj) {
            bf16x8 bv = *(const bf16x8*)(KtVtb + (size_t)(tj * 16 + lr) * 64 + kb);
            aacc[tj] = __builtin_amdgcn_mfma_f32_16x16x32_bf16(a, bv, aacc[tj], 0, 0, 0);
        }
    }
#pragma unroll
    for (int tj = 0; tj < 4; ++tj)
#pragma unroll
        for (int r = 0; r < 4; ++r) {
            float hp = aacc[tj][r] + Hrow[(rw + q * 4 + r) * 64 + tj * 16 + lr];
            As[(rw + q * 4 + r) * DPAD + tj * 16 + lr] = (__bf16)hp;
        }

    // ---- out = Hp @ outW^T + outb, LN ----
    f32x4 oacc[4];
#pragma unroll
    for (int tj = 0; tj < 4; ++tj) oacc[tj] = (f32x4)(0.0f);
#pragma unroll
    for (int ks = 0; ks < 2; ++ks) {
        int kb = ks * 32 + q * 8;
        bf16x8 a = *(const bf16x8*)&As[(rw + lr) * DPAD + kb];
#pragma unroll
        for (int tj = 0; tj < 4; ++tj) {
            bf16x8 bv = *(const bf16x8*)(outWb + (size_t)(tj * 16 + lr) * 64 + kb);
            oacc[tj] = __builtin_amdgcn_mfma_f32_16x16x32_bf16(a, bv, oacc[tj], 0, 0, 0);
        }
    }
    float biasv[4], gv[4], bv2[4];
#pragma unroll
    for (int tj = 0; tj < 4; ++tj) {
        int col = tj * 16 + lr;
        biasv[tj] = outb[col]; gv[tj] = g[col]; bv2[tj] = bb[col];
    }
#pragma unroll
    for (int r = 0; r < 4; ++r) {
        float v[4];
        float s = 0.f;
#pragma unroll
        for (int tj = 0; tj < 4; ++tj) { v[tj] = oacc[tj][r] + biasv[tj]; s += v[tj]; }
        s += __shfl_xor(s, 1, 64); s += __shfl_xor(s, 2, 64);
        s += __shfl_xor(s, 4, 64); s += __shfl_xor(s, 8, 64);
        float mu = s * (1.0f / 64.0f);
        float qv = 0.f;
#pragma unroll
        for (int tj = 0; tj < 4; ++tj) { float d = v[tj] - mu; qv += d * d; }
        qv += __shfl_xor(qv, 1, 64); qv += __shfl_xor(qv, 2, 64);
        qv += __shfl_xor(qv, 4, 64); qv += __shfl_xor(qv, 8, 64);
        float rstd = rsqrtf(qv * (1.0f / 64.0f) + 1e-5f);
#pragma unroll
        for (int tj = 0; tj < 4; ++tj)
            Ps[(rw + q * 4 + r) * DPAD + tj * 16 + lr] =
                (__bf16)((v[tj] - mu) * rstd * gv[tj] + bv2[tj]);
    }
    __syncthreads();

    size_t base = (size_t)blockIdx.x * 4096;
    {
        int r = tid >> 2, c0 = (tid & 3) * 16;
        *(bf16x8*)(memval + base + (size_t)r * 64 + c0)     = *(const bf16x8*)&Ms[r * DPAD + c0];
        *(bf16x8*)(memval + base + (size_t)r * 64 + c0 + 8) = *(const bf16x8*)&Ms[r * DPAD + c0 + 8];
        *(bf16x8*)(Hn + base + (size_t)r * 64 + c0)         = *(const bf16x8*)&Ps[r * DPAD + c0];
        *(bf16x8*)(Hn + base + (size_t)r * 64 + c0 + 8)     = *(const bf16x8*)&Ps[r * DPAD + c0 + 8];
    }
    int bt = blockIdx.x >> 4, n0b = (blockIdx.x & 15) * 64;
    size_t tbase = (size_t)bt * 64 * N_;
#pragma unroll
    for (int i = 0; i < 2; ++i) {
        int d = (tid >> 3) + i * 32;
        int n8 = (tid & 7) * 8;
        bf16x8 v;
#pragma unroll
        for (int j = 0; j < 8; ++j) {
            int jj = (j + tid) & 7;
            v[jj] = Ps[(n8 + jj) * DPAD + d];
        }
        *(bf16x8*)(Ht + tbase + (size_t)d * N_ + n0b + n8) = v;
    }
}

// ---------- K2: mv = mean_t memval ----------
__global__ void k_mvred(const __bf16* __restrict__ memval, __bf16* __restrict__ mvb) {
    int idx = (blockIdx.x * 256 + threadIdx.x) * 4;
    int b = idx >> 16;
    int off = idx & 65535;
    const __bf16* p = memval + (size_t)b * T_ * 65536 + off;
    float a0 = 0.f, a1 = 0.f, a2 = 0.f, a3 = 0.f;
#pragma unroll
    for (int t = 0; t < T_; ++t) {
        bf16x4 v = *(const bf16x4*)(p + (size_t)t * 65536);
        a0 += (float)v[0]; a1 += (float)v[1]; a2 += (float)v[2]; a3 += (float)v[3];
    }
    bf16x4 o;
    o[0] = (__bf16)(a0 * (1.0f / 12.0f)); o[1] = (__bf16)(a1 * (1.0f / 12.0f));
    o[2] = (__bf16)(a2 * (1.0f / 12.0f)); o[3] = (__bf16)(a3 * (1.0f / 12.0f));
    *(bf16x4*)(mvb + idx) = o;
}

// ---------- K3: MFMA A_dynamic + A_fused, in-register row softmax ----------
__global__ void k_adyn_mfma(const __bf16* __restrict__ mvb_all, const float* __restrict__ Ast,
                            const float* __restrict__ dinv, const float* __restrict__ beta,
                            float* __restrict__ Adyn, float* __restrict__ Afu,
                            __bf16* __restrict__ Afb) {
    __shared__ __align__(16) __bf16 As[16 * DPAD];
    __shared__ __align__(16) __bf16 Bs[256 * DPAD];
    __shared__ float redm[4][16];
    __shared__ float reds[4][16];
    int tid = threadIdx.x;
    int b = blockIdx.x >> 6, n0 = (blockIdx.x & 63) * 16;
    const __bf16* mvb = mvb_all + (size_t)b * N_ * 64;
    {
        int r = tid >> 4, c4 = (tid & 15) * 4;
        *(bf16x4*)&As[r * DPAD + c4] = *(const bf16x4*)(mvb + (size_t)(n0 + r) * 64 + c4);
    }
    int w = tid >> 6, lane = tid & 63, q = lane >> 4, lr = lane & 15;
    f32x4 acc[4][4];
#pragma unroll
    for (int c = 0; c < 4; ++c)
#pragma unroll
        for (int tj = 0; tj < 4; ++tj) acc[c][tj] = (f32x4)(0.0f);
    int brow = tid >> 3, bcol = (tid & 7) * 8;
    for (int c = 0; c < 4; ++c) {
        __syncthreads();
#pragma unroll
        for (int i = 0; i < 8; ++i) {
            int r = brow + i * 32;
            *(bf16x8*)&Bs[r * DPAD + bcol] = *(const bf16x8*)(mvb + (size_t)(c * 256 + r) * 64 + bcol);
        }
        __syncthreads();
#pragma unroll
        for (int ks = 0; ks < 2; ++ks) {
            int kb = ks * 32 + q * 8;
            bf16x8 a0 = *(const bf16x8*)&As[lr * DPAD + kb];
#pragma unroll
            for (int tj = 0; tj < 4; ++tj) {
                bf16x8 bv = *(const bf16x8*)&Bs[(w * 64 + tj * 16 + lr) * DPAD + kb];
                acc[c][tj] = __builtin_amdgcn_mfma_f32_16x16x32_bf16(a0, bv, acc[c][tj], 0, 0, 0);
            }
        }
    }
    float mrow[4];
#pragma unroll
    for (int rr = 0; rr < 4; ++rr) {
        float m = -3.4e38f;
#pragma unroll
        for (int c = 0; c < 4; ++c)
#pragma unroll
            for (int tj = 0; tj < 4; ++tj) m = fmaxf(m, acc[c][tj][rr]);
        m = fmaxf(m, __shfl_xor(m, 1, 64)); m = fmaxf(m, __shfl_xor(m, 2, 64));
        m = fmaxf(m, __shfl_xor(m, 4, 64)); m = fmaxf(m, __shfl_xor(m, 8, 64));
        mrow[rr] = m;
    }
    if (lr == 0) {
#pragma unroll
        for (int rr = 0; rr < 4; ++rr) redm[w][q * 4 + rr] = mrow[rr];
    }
    __syncthreads();
    float mg[4];
#pragma unroll
    for (int rr = 0; rr < 4; ++rr) {
        int row = q * 4 + rr;
        mg[rr] = fmaxf(fmaxf(redm[0][row], redm[1][row]), fmaxf(redm[2][row], redm[3][row]));
    }
    float srow[4] = {0.f, 0.f, 0.f, 0.f};
#pragma unroll
    for (int c = 0; c < 4; ++c)
#pragma unroll
        for (int tj = 0; tj < 4; ++tj)
#pragma unroll
            for (int rr = 0; rr < 4; ++rr) {
                float e = __expf(0.125f * (acc[c][tj][rr] - mg[rr]));
                acc[c][tj][rr] = e;
                srow[rr] += e;
            }
#pragma unroll
    for (int rr = 0; rr < 4; ++rr) {
        float s = srow[rr];
        s += __shfl_xor(s, 1, 64); s += __shfl_xor(s, 2, 64);
        s += __shfl_xor(s, 4, 64); s += __shfl_xor(s, 8, 64);
        srow[rr] = s;
    }
    if (lr == 0) {
#pragma unroll
        for (int rr = 0; rr < 4; ++rr) reds[w][q * 4 + rr] = srow[rr];
    }
    __syncthreads();
    float inv[4];
#pragma unroll
    for (int rr = 0; rr < 4; ++rr) {
        int row = q * 4 + rr;
        inv[rr] = 1.0f / (reds[0][row] + reds[1][row] + reds[2][row] + reds[3][row]);
    }
    float bta = fminf(fmaxf(beta[0], 0.0f), 1.0f);
    float omb = 1.0f - bta;
    float dc[4][4];
#pragma unroll
    for (int c = 0; c < 4; ++c)
#pragma unroll
        for (int tj = 0; tj < 4; ++tj) dc[c][tj] = dinv[c * 256 + w * 64 + tj * 16 + lr];
#pragma unroll
    for (int rr = 0; rr < 4; ++rr) {
        int n = n0 + q * 4 + rr;
        float dn = omb * dinv[n];
        size_t ro = ((size_t)b * N_ + n) * N_;
        const float* arow = Ast + (size_t)n * N_;
#pragma unroll
        for (int c = 0; c < 4; ++c)
#pragma unroll
            for (int tj = 0; tj < 4; ++tj) {
                int col = c * 256 + w * 64 + tj * 16 + lr;
                float p = acc[c][tj][rr] * inv[rr];
                float fu = bta * p + dn * arow[col] * dc[c][tj];
                Adyn[ro + col] = p;
                Afu[ro + col] = fu;
                Afb[ro + col] = (__bf16)fu;
            }
    }
}

// ---------- K4: hop 1 — LDS-staged MFMA K-loop (proven round-3 structure) ----------
__global__ void k_diffuse1(const __bf16* __restrict__ Afb, const __bf16* __restrict__ Xt,
                           __bf16* __restrict__ Xn_out, __bf16* __restrict__ Xt_out) {
    __shared__ __align__(16) __bf16 As[128 * DPAD];
    __shared__ __align__(16) __bf16 Bs[64 * DPAD];
    int tid = threadIdx.x;
    int bt = blockIdx.y, b = bt / T_;
    int n0 = blockIdx.x * 128;
    const __bf16* A = Afb + (size_t)b * N_ * N_ + (size_t)n0 * N_;
    const __bf16* X = Xt + (size_t)bt * 64 * N_;
    int w = tid >> 6, lane = tid & 63, q = lane >> 4, lr = lane & 15;
    int mw = w * 32;
    f32x4 acc[2][4];
#pragma unroll
    for (int i = 0; i < 2; ++i)
#pragma unroll
        for (int j = 0; j < 4; ++j) acc[i][j] = (f32x4)(0.0f);
    int arow = tid >> 3, acol = (tid & 7) * 8;
    for (int kc = 0; kc < 16; ++kc) {
        if (kc) __syncthreads();
#pragma unroll
        for (int i = 0; i < 4; ++i) {
            int r = arow + i * 32;
            *(bf16x8*)&As[r * DPAD + acol] = *(const bf16x8*)(A + (size_t)r * N_ + kc * 64 + acol);
        }
#pragma unroll
        for (int i = 0; i < 2; ++i) {
            int r = arow + i * 32;
            *(bf16x8*)&Bs[r * DPAD + acol] = *(const bf16x8*)(X + (size_t)r * N_ + kc * 64 + acol);
        }
        __syncthreads();
#pragma unroll
        for (int ks = 0; ks < 2; ++ks) {
            int kb = ks * 32 + q * 8;
            bf16x8 a0 = *(const bf16x8*)&As[(mw + lr) * DPAD + kb];
            bf16x8 a1 = *(const bf16x8*)&As[(mw + 16 + lr) * DPAD + kb];
#pragma unroll
            for (int tj = 0; tj < 4; ++tj) {
                bf16x8 bf = *(const bf16x8*)&Bs[(tj * 16 + lr) * DPAD + kb];
                acc[0][tj] = __builtin_amdgcn_mfma_f32_16x16x32_bf16(a0, bf, acc[0][tj], 0, 0, 0);
                acc[1][tj] = __builtin_amdgcn_mfma_f32_16x16x32_bf16(a1, bf, acc[1][tj], 0, 0, 0);
            }
        }
    }
    __syncthreads();
    __bf16* Cs = As;
#pragma unroll
    for (int ti = 0; ti < 2; ++ti)
#pragma unroll
        for (int tj = 0; tj < 4; ++tj)
#pragma unroll
            for (int r = 0; r < 4; ++r)
                Cs[(mw + ti * 16 + q * 4 + r) * DPAD + tj * 16 + lr] = (__bf16)acc[ti][tj][r];
    __syncthreads();
    size_t obase = (size_t)bt * N_ * 64 + (size_t)n0 * 64;
#pragma unroll
    for (int i = 0; i < 2; ++i) {
        int r = (tid >> 2) + i * 64, c0 = (tid & 3) * 16;
        *(bf16x8*)(Xn_out + obase + (size_t)r * 64 + c0)     = *(const bf16x8*)&Cs[r * DPAD + c0];
        *(bf16x8*)(Xn_out + obase + (size_t)r * 64 + c0 + 8) = *(const bf16x8*)&Cs[r * DPAD + c0 + 8];
    }
    size_t tbase = (size_t)bt * 64 * N_;
#pragma unroll
    for (int i = 0; i < 4; ++i) {
        int d = (tid >> 4) + i * 16;
        int n8 = (tid & 15) * 8;
        bf16x8 v;
#pragma unroll
        for (int j = 0; j < 8; ++j) {
            int jj = (j + tid) & 7;
            v[jj] = Cs[(n8 + jj) * DPAD + d];
        }
        *(bf16x8*)(Xt_out + tbase + (size_t)d * N_ + n0 + n8) = v;
    }
}

// ---------- K5: hop 2 (LDS-staged) + proj + LN fused ----------
__global__ void k_diffuse2_proj(const __bf16* __restrict__ Afb, const __bf16* __restrict__ X1t,
                                const __bf16* __restrict__ Hn, const __bf16* __restrict__ X1n,
                                const __bf16* __restrict__ PWb, const float* __restrict__ pb,
                                const float* __restrict__ g, const float* __restrict__ bb,
                                float* __restrict__ out) {
    __shared__ __align__(16) __bf16 As[128 * DPAD];
    __shared__ __align__(16) __bf16 Bs[64 * DPAD];
    int tid = threadIdx.x;
    int bt = blockIdx.y, b = bt / T_;
    int n0 = blockIdx.x * 128;
    const __bf16* A = Afb + (size_t)b * N_ * N_ + (size_t)n0 * N_;
    const __bf16* X = X1t + (size_t)bt * 64 * N_;
    int w = tid >> 6, lane = tid & 63, q = lane >> 4, lr = lane & 15;
    int mw = w * 32;
    f32x4 acc[2][4];
#pragma unroll
    for (int i = 0; i < 2; ++i)
#pragma unroll
        for (int j = 0; j < 4; ++j) acc[i][j] = (f32x4)(0.0f);
    int arow = tid >> 3, acol = (tid & 7) * 8;
    for (int kc = 0; kc < 16; ++kc) {
        if (kc) __syncthreads();
#pragma unroll
        for (int i = 0; i < 4; ++i) {
            int r = arow + i * 32;
            *(bf16x8*)&As[r * DPAD + acol] = *(const bf16x8*)(A + (size_t)r * N_ + kc * 64 + acol);
        }
#pragma unroll
        for (int i = 0; i < 2; ++i) {
            int r = arow + i * 32;
            *(bf16x8*)&Bs[r * DPAD + acol] = *(const bf16x8*)(X + (size_t)r * N_ + kc * 64 + acol);
        }
        __syncthreads();
#pragma unroll
        for (int ks = 0; ks < 2; ++ks) {
            int kb = ks * 32 + q * 8;
            bf16x8 a0 = *(const bf16x8*)&As[(mw + lr) * DPAD + kb];
            bf16x8 a1 = *(const bf16x8*)&As[(mw + 16 + lr) * DPAD + kb];
#pragma unroll
            for (int tj = 0; tj < 4; ++tj) {
                bf16x8 bf = *(const bf16x8*)&Bs[(tj * 16 + lr) * DPAD + kb];
                acc[0][tj] = __builtin_amdgcn_mfma_f32_16x16x32_bf16(a0, bf, acc[0][tj], 0, 0, 0);
                acc[1][tj] = __builtin_amdgcn_mfma_f32_16x16x32_bf16(a1, bf, acc[1][tj], 0, 0, 0);
            }
        }
    }
    __syncthreads();   // everyone done reading As/Bs for the hop
    // X2 -> LDS (wave-private rows; no further barrier needed)
    __bf16* Cs = As;
#pragma unroll
    for (int ti = 0; ti < 2; ++ti)
#pragma unroll
        for (int tj = 0; tj < 4; ++tj)
#pragma unroll
            for (int r = 0; r < 4; ++r)
                Cs[(mw + ti * 16 + q * 4 + r) * DPAD + tj * 16 + lr] = (__bf16)acc[ti][tj][r];
    // proj: cat(H', X1, X2) @ PW^T
    f32x4 pacc[2][4];
#pragma unroll
    for (int i = 0; i < 2; ++i)
#pragma unroll
        for (int j = 0; j < 4; ++j) pacc[i][j] = (f32x4)(0.0f);
    size_t row0 = (size_t)bt * N_ + n0;
#pragma unroll
    for (int c = 0; c < 2; ++c) {
        const __bf16* S = (c ? X1n : Hn) + row0 * 64;
#pragma unroll
        for (int ks = 0; ks < 2; ++ks) {
            int kb = ks * 32 + q * 8;
            bf16x8 a0 = *(const bf16x8*)(S + (size_t)(mw + lr) * 64 + kb);
            bf16x8 a1 = *(const bf16x8*)(S + (size_t)(mw + 16 + lr) * 64 + kb);
#pragma unroll
            for (int tj = 0; tj < 4; ++tj) {
                bf16x8 bv = *(const bf16x8*)(PWb + (size_t)(tj * 16 + lr) * 192 + c * 64 + kb);
                pacc[0][tj] = __builtin_amdgcn_mfma_f32_16x16x32_bf16(a0, bv, pacc[0][tj], 0, 0, 0);
                pacc[1][tj] = __builtin_amdgcn_mfma_f32_16x16x32_bf16(a1, bv, pacc[1][tj], 0, 0, 0);
            }
        }
    }
#pragma unroll
    for (int ks = 0; ks < 2; ++ks) {
        int kb = ks * 32 + q * 8;
        bf16x8 a0 = *(const bf16x8*)&Cs[(mw + lr) * DPAD + kb];
        bf16x8 a1 = *(const bf16x8*)&Cs[(mw + 16 + lr) * DPAD + kb];
#pragma unroll
        for (int tj = 0; tj < 4; ++tj) {
            bf16x8 bv = *(const bf16x8*)(PWb + (size_t)(tj * 16 + lr) * 192 + 128 + kb);
            pacc[0][tj] = __builtin_amdgcn_mfma_f32_16x16x32_bf16(a0, bv, pacc[0][tj], 0, 0, 0);
            pacc[1][tj] = __builtin_amdgcn_mfma_f32_16x16x32_bf16(a1, bv, pacc[1][tj], 0, 0, 0);
        }
    }
    // bias + LN epilogue
    float pbv[4], gv[4], bv2[4];
#pragma unroll
    for (int tj = 0; tj < 4; ++tj) {
        int col = tj * 16 + lr;
        pbv[tj] = pb[col]; gv[tj] = g[col]; bv2[tj] = bb[col];
    }
#pragma unroll
    for (int ti = 0; ti < 2; ++ti) {
#pragma unroll
        for (int r = 0; r < 4; ++r) {
            float v[4];
            float s = 0.f;
#pragma unroll
            for (int tj = 0; tj < 4; ++tj) { v[tj] = pacc[ti][tj][r] + pbv[tj]; s += v[tj]; }
            s += __shfl_xor(s, 1, 64); s += __shfl_xor(s, 2, 64);
            s += __shfl_xor(s, 4, 64); s += __shfl_xor(s, 8, 64);
            float mu = s * (1.0f / 64.0f);
            float qv = 0.f;
#pragma unroll
            for (int tj = 0; tj < 4; ++tj) { float d = v[tj] - mu; qv += d * d; }
            qv += __shfl_xor(qv, 1, 64); qv += __shfl_xor(qv, 2, 64);
            qv += __shfl_xor(qv, 4, 64); qv += __shfl_xor(qv, 8, 64);
            float rstd = rsqrtf(qv * (1.0f / 64.0f) + 1e-5f);
            size_t row = row0 + mw + ti * 16 + q * 4 + r;
#pragma unroll
            for (int tj = 0; tj < 4; ++tj)
                out[row * 64 + tj * 16 + lr] = (v[tj] - mu) * rstd * gv[tj] + bv2[tj];
        }
    }
}

// ---------- launch ----------
extern "C" void kernel_launch(void* const* d_in, const int* in_sizes, int n_in,
                              void* d_out, int out_size, void* d_ws, size_t ws_size,
                              hipStream_t stream) {
    const float* H    = (const float*)d_in[0];
    const float* Ast  = (const float*)d_in[1];
    const float* WQ   = (const float*)d_in[2];
    const float* WK   = (const float*)d_in[3];
    const float* WV   = (const float*)d_in[4];
    const float* PHI  = (const float*)d_in[5];
    const float* outW = (const float*)d_in[6];
    const float* outb = (const float*)d_in[7];
    const float* smag = (const float*)d_in[8];
    const float* smab = (const float*)d_in[9];
    const float* beta = (const float*)d_in[10];
    const float* PW   = (const float*)d_in[11];
    const float* pb   = (const float*)d_in[12];
    const float* aggg = (const float*)d_in[13];
    const float* aggb = (const float*)d_in[14];

    float* out  = (float*)d_out;
    float* Hsp  = out;
    float* Adyn = out + (size_t)ROWS_ * 64;
    float* Afu  = Adyn + (size_t)B_ * N_ * N_;

    __bf16* memval = (__bf16*)d_ws;                    // [BT,N,64]
    __bf16* Hn   = memval + (size_t)ROWS_ * 64;
    __bf16* Ht   = Hn + (size_t)ROWS_ * 64;
    __bf16* X1n  = Ht + (size_t)ROWS_ * 64;
    __bf16* X1t  = X1n + (size_t)ROWS_ * 64;
    __bf16* Afb  = X1t + (size_t)ROWS_ * 64;           // [B,N,N]
    __bf16* mvb  = Afb + (size_t)B_ * N_ * N_;         // [B,N,64]
    __bf16* phiKb = mvb + (size_t)B_ * N_ * 64;
    __bf16* Vtb   = phiKb + M_ * E_;                   // [64][32] padded
    __bf16* KtVtb = Vtb + 64 * 32;
    __bf16* WQb   = KtVtb + 4096;
    __bf16* outWb = WQb + 4096;
    __bf16* PWb   = outWb + 4096;                      // [64][192]
    float*  dinv  = (float*)(PWb + 64 * 192);

    k_precompute<<<1, 256, 0, stream>>>(PHI, WK, WV, WQ, outW, PW,
                                        phiKb, Vtb, KtVtb, WQb, outWb, PWb);
    k_dinv<<<N_, 256, 0, stream>>>(Ast, dinv);
    k_spine<<<ROWS_ / 64, 256, 0, stream>>>(H, WQb, phiKb, Vtb, KtVtb, outWb,
                                            outb, smag, smab, memval, Hn, Ht);
    k_mvred<<<(B_ * N_ * 64 / 4) / 256, 256, 0, stream>>>(memval, mvb);
    k_adyn_mfma<<<B_ * N_ / 16, 256, 0, stream>>>(mvb, Ast, dinv, beta, Adyn, Afu, Afb);
    k_diffuse1<<<dim3(8, BT_), 256, 0, stream>>>(Afb, Ht, X1n, X1t);
    k_diffuse2_proj<<<dim3(8, BT_), 256, 0, stream>>>(Afb, X1t, Hn, X1n, PWb,
                                                      pb, aggg, aggb, Hsp);
}